// Round 10
// baseline (244.540 us; speedup 1.0000x reference)
//
#include <hip/hip_runtime.h>

// GAT forward — MFMA GEMM + two-level bucket CSR + weighted gather (5 launches):
//   1. front (fused): blocks [0,GB): MFMA gemm BM=128 -> ftb + head-0 scores.
//      One 32KB W_lds build serves TWO 64-row subtiles; each W fragment read
//      feeds 2 MFMAs. W_lds reused as 32KB C_lds for both subtiles' transpose.
//      blocks [GB,GB+NBLK): bhist per-(block,bucket) LDS histogram (bucket=dst>>7)
//   2. scan1: exclusive scan of bh[bucket][block] per 1024-chunk + raw totals
//   3. bscatter: local pscan; 4-edge batched loop (8 gathers in flight);
//      cur[] init at base offset (pos = atomicAdd directly).
//   4. bsort: per-bucket (128 dsts) counting sort; single global read (records
//      in registers); softmax stores w=exp in pass B (1 exp per record).
//   5. aggregate: block=4 waves=4 consecutive dsts; edata staged to LDS;
//      16 lanes/edge x 4 slots; f32x2 accumulate.
//
// ws: ftb | s_l | s_r | bh (M u32) | S (M u32) | partials (1024) |
//     offsets (N u32) | staged/edata (E uint2)

#define ALPHA 0.2f
#define NBLK 512           // partition blocks
#define BBITS 7
#define BSIZE 128          // dsts per bucket
#define CAP 2816           // bsort LDS record capacity (mean 2048, +17 sigma)
#define REGN 11            // ceil(CAP/256) register-held records per thread
#define ESLOTS 1024        // aggregate edata LDS staging slots (mean span 64)

typedef __attribute__((ext_vector_type(8))) short bf16x8;
typedef __attribute__((ext_vector_type(8))) unsigned short u16x8;
typedef __attribute__((ext_vector_type(4))) float f32x4;
typedef __attribute__((ext_vector_type(2))) float f32x2;

__device__ __forceinline__ unsigned short f2bf(float f) {
    unsigned u = __float_as_uint(f);
    unsigned r = (u + 0x7FFFu + ((u >> 16) & 1u)) >> 16;   // RNE
    return (unsigned short)r;
}

// ---------- front: fused MFMA GEMM (BM=128) + bhist ----------
__global__ __launch_bounds__(256) void front_kernel(
        const float* __restrict__ A, const float* __restrict__ W,
        const float* __restrict__ attn_l, const float* __restrict__ attn_r,
        unsigned short* __restrict__ ftb,
        float* __restrict__ s_l, float* __restrict__ s_r, int N, int GB,
        const int* __restrict__ dst, unsigned* __restrict__ bh,
        int E, int nbucket, int slice) {
    __shared__ char smem[32768];
    const int tid = threadIdx.x;

    if (blockIdx.x >= (unsigned)GB) {
        // ---------------- bhist body ----------------
        unsigned* cnt = (unsigned*)smem;
        for (int i = tid; i < nbucket; i += 256) cnt[i] = 0u;
        __syncthreads();
        const int b = blockIdx.x - GB;
        int s0 = b * slice, s1 = min(s0 + slice, E);
        for (int i = s0 + tid; i < s1; i += 256)
            atomicAdd(&cnt[((unsigned)dst[i]) >> BBITS], 1u);
        __syncthreads();
        for (int k = tid; k < nbucket; k += 256)
            bh[(size_t)k * NBLK + b] = cnt[k];
        return;
    }

    // ---------------- gemm body (128 rows per block) ----------------
    u16x8* W_lds = (u16x8*)smem;                 // 128 n x 16 chunks (32 KB)
    const int block_row = blockIdx.x * 128;

    // build swizzled bf16 W^T in-block; coalesced over n, L2-served
    for (int i = tid; i < 2048; i += 256) {
        int n = i & 127, c = i >> 7;
        u16x8 v;
        #pragma unroll
        for (int j = 0; j < 8; ++j) v[j] = f2bf(W[(c * 8 + j) * 128 + n]);
        W_lds[n * 16 + (c ^ (n & 7))] = v;
    }

    const int wv = tid >> 6;
    const int lane = tid & 63;
    const int lm = lane & 15;
    const int quad = lane >> 4;
    const int am0 = block_row + wv * 16 + lm;        // subtile-0 row
    const int am1 = am0 + 64;                        // subtile-1 row
    const bool ok0 = (am0 < N), ok1 = (am1 < N);

    // A fragments direct from global (16B/lane contiguous per k-chunk)
    bf16x8 a0[4], a1[4];
    #pragma unroll
    for (int ks = 0; ks < 4; ++ks) {
        int c = ks * 4 + quad;
        float4 v0 = make_float4(0.f, 0.f, 0.f, 0.f), v1 = v0;
        float4 w0 = v0, w1 = v0;
        if (ok0) {
            const float4* p = (const float4*)(A + (size_t)am0 * 128 + c * 8);
            v0 = p[0]; v1 = p[1];
        }
        if (ok1) {
            const float4* p = (const float4*)(A + (size_t)am1 * 128 + c * 8);
            w0 = p[0]; w1 = p[1];
        }
        u16x8 u;
        u[0] = f2bf(v0.x); u[1] = f2bf(v0.y); u[2] = f2bf(v0.z); u[3] = f2bf(v0.w);
        u[4] = f2bf(v1.x); u[5] = f2bf(v1.y); u[6] = f2bf(v1.z); u[7] = f2bf(v1.w);
        a0[ks] = *(const bf16x8*)&u;
        u[0] = f2bf(w0.x); u[1] = f2bf(w0.y); u[2] = f2bf(w0.z); u[3] = f2bf(w0.w);
        u[4] = f2bf(w1.x); u[5] = f2bf(w1.y); u[6] = f2bf(w1.z); u[7] = f2bf(w1.w);
        a1[ks] = *(const bf16x8*)&u;
    }
    __syncthreads();   // W_lds ready

    f32x4 acc0[8], acc1[8];
    #pragma unroll
    for (int t = 0; t < 8; ++t) { acc0[t] = (f32x4)(0.f); acc1[t] = (f32x4)(0.f); }

    #pragma unroll
    for (int ks = 0; ks < 4; ++ks) {
        int c = ks * 4 + quad;
        #pragma unroll
        for (int t = 0; t < 8; ++t) {
            int n = t * 16 + lm;
            bf16x8 bf = *(const bf16x8*)&W_lds[n * 16 + (c ^ (n & 7))];
            acc0[t] = __builtin_amdgcn_mfma_f32_16x16x32_bf16(a0[ks], bf, acc0[t], 0, 0, 0);
            acc1[t] = __builtin_amdgcn_mfma_f32_16x16x32_bf16(a1[ks], bf, acc1[t], 0, 0, 0);
        }
    }

    // fused head-0 scores (cols 0..31 live in frags 0,1) for both subtiles
    {
        float al0 = attn_l[lm], al1 = attn_l[16 + lm];
        float ar0 = attn_r[lm], ar1 = attn_r[16 + lm];
        #pragma unroll
        for (int r = 0; r < 4; ++r) {
            float pl0 = acc0[0][r] * al0 + acc0[1][r] * al1;
            float pr0 = acc0[0][r] * ar0 + acc0[1][r] * ar1;
            float pl1 = acc1[0][r] * al0 + acc1[1][r] * al1;
            float pr1 = acc1[0][r] * ar0 + acc1[1][r] * ar1;
            #pragma unroll
            for (int mask = 1; mask < 16; mask <<= 1) {
                pl0 += __shfl_xor(pl0, mask, 64);
                pr0 += __shfl_xor(pr0, mask, 64);
                pl1 += __shfl_xor(pl1, mask, 64);
                pr1 += __shfl_xor(pr1, mask, 64);
            }
            if (lm == 0) {
                int row = block_row + wv * 16 + quad * 4 + r;
                if (row < N) { s_l[row] = pl0; s_r[row] = pr0; }
                if (row + 64 < N) { s_l[row + 64] = pl1; s_r[row + 64] = pr1; }
            }
        }
    }

    // transpose both subtiles through LDS (reusing W_lds: 128 rows x 128 x 2B = 32KB)
    __syncthreads();   // all waves done reading W_lds
    unsigned short* C_lds = (unsigned short*)smem;
    #pragma unroll
    for (int t = 0; t < 8; ++t) {
        #pragma unroll
        for (int r = 0; r < 4; ++r) {
            int mrow = wv * 16 + quad * 4 + r;
            C_lds[mrow * 128 + t * 16 + lm] = f2bf(acc0[t][r]);
            C_lds[(mrow + 64) * 128 + t * 16 + lm] = f2bf(acc1[t][r]);
        }
    }
    __syncthreads();
    for (int l = tid; l < 2048; l += 256) {
        int m = l >> 4, c = l & 15;
        int row = block_row + m;
        if (row < N)
            *(u16x8*)(ftb + (size_t)row * 128 + c * 8) = *(const u16x8*)&C_lds[m * 128 + c * 8];
    }
}

// ---------- scan1: block-local exclusive scan (1024/block) + raw totals ----------
__global__ __launch_bounds__(256) void scan1_kernel(const unsigned* __restrict__ counts,
                                                    unsigned* __restrict__ S,
                                                    unsigned* __restrict__ partials, int M) {
    __shared__ unsigned sh[256];
    const int tid = threadIdx.x;
    const int base = blockIdx.x * 1024 + tid * 4;
    unsigned v[4];
    unsigned s = 0;
    #pragma unroll
    for (int k = 0; k < 4; ++k) {
        int idx = base + k;
        v[k] = (idx < M) ? counts[idx] : 0u;
        s += v[k];
    }
    sh[tid] = s;
    __syncthreads();
    for (int off = 1; off < 256; off <<= 1) {
        unsigned t = (tid >= off) ? sh[tid - off] : 0u;
        __syncthreads();
        sh[tid] += t;
        __syncthreads();
    }
    if (tid == 255) partials[blockIdx.x] = sh[255];   // RAW total (no scan2)
    unsigned run = (tid == 0) ? 0u : sh[tid - 1];
    #pragma unroll
    for (int k = 0; k < 4; ++k) {
        int idx = base + k;
        if (idx < M) S[idx] = run;
        run += v[k];
    }
}

// local exclusive scan of <=1024 raw partials into pscan[] (4/thread; all enter)
__device__ __forceinline__ void local_pscan4(const unsigned* __restrict__ partials,
                                             unsigned* pscan, unsigned* tsh,
                                             int NB, int tid) {
    unsigned v[4];
    unsigned s = 0;
    #pragma unroll
    for (int k = 0; k < 4; ++k) {
        int idx = tid * 4 + k;
        v[k] = (idx < NB) ? partials[idx] : 0u;
        s += v[k];
    }
    tsh[tid] = s;
    __syncthreads();
    for (int off = 1; off < 256; off <<= 1) {
        unsigned t = (tid >= off) ? tsh[tid - off] : 0u;
        __syncthreads();
        tsh[tid] += t;
        __syncthreads();
    }
    unsigned run = (tid == 0) ? 0u : tsh[tid - 1];
    #pragma unroll
    for (int k = 0; k < 4; ++k) {
        int idx = tid * 4 + k;
        if (idx < NB) pscan[idx] = run;
        run += v[k];
    }
    __syncthreads();
}

// ---------- bscatter: staged[pos] = {src | dlow<<20, leaky_score} ----------
// cur[k] initialized AT the global base (basel folded away); 4-edge batched
// main loop keeps 8 random gathers in flight per lane.
__global__ __launch_bounds__(256) void bscatter_kernel(
        const int* __restrict__ src, const int* __restrict__ dst,
        const float* __restrict__ s_l, const float* __restrict__ s_r,
        const unsigned* __restrict__ S, const unsigned* __restrict__ partials,
        uint2* __restrict__ staged, int E, int nbucket, int slice, int NB) {
    __shared__ unsigned pscan[512];
    __shared__ unsigned tsh[256];
    __shared__ unsigned cur[800];
    const int b = blockIdx.x;
    const int tid = threadIdx.x;
    local_pscan4(partials, pscan, tsh, NB, tid);
    for (int k = tid; k < nbucket; k += 256) {
        unsigned idx = (unsigned)k * NBLK + b;
        cur[k] = S[idx] + pscan[idx >> 10];
    }
    __syncthreads();
    const int s0 = b * slice, s1 = min(s0 + slice, E);
    int i = s0 + tid;
    // 4-edge batched steady loop: all loads issued before any compute
    for (; i + 768 < s1; i += 1024) {
        int sa = src[i],       da = dst[i];
        int sb = src[i + 256], db = dst[i + 256];
        int sc = src[i + 512], dc = dst[i + 512];
        int sd = src[i + 768], dd = dst[i + 768];
        float la = s_l[sa], ra = s_r[da];
        float lb = s_l[sb], rb = s_r[db];
        float lc = s_l[sc], rc = s_r[dc];
        float ld = s_l[sd], rd = s_r[dd];
        float xa = la + ra, xb = lb + rb, xc = lc + rc, xd = ld + rd;
        float ea = (xa > 0.f) ? xa : ALPHA * xa;
        float eb = (xb > 0.f) ? xb : ALPHA * xb;
        float ec = (xc > 0.f) ? xc : ALPHA * xc;
        float ed = (xd > 0.f) ? xd : ALPHA * xd;
        unsigned pa = atomicAdd(&cur[((unsigned)da) >> BBITS], 1u);
        unsigned pb = atomicAdd(&cur[((unsigned)db) >> BBITS], 1u);
        unsigned pc = atomicAdd(&cur[((unsigned)dc) >> BBITS], 1u);
        unsigned pd = atomicAdd(&cur[((unsigned)dd) >> BBITS], 1u);
        staged[pa] = make_uint2((unsigned)sa | (((unsigned)da & (BSIZE - 1)) << 20), __float_as_uint(ea));
        staged[pb] = make_uint2((unsigned)sb | (((unsigned)db & (BSIZE - 1)) << 20), __float_as_uint(eb));
        staged[pc] = make_uint2((unsigned)sc | (((unsigned)dc & (BSIZE - 1)) << 20), __float_as_uint(ec));
        staged[pd] = make_uint2((unsigned)sd | (((unsigned)dd & (BSIZE - 1)) << 20), __float_as_uint(ed));
    }
    for (; i < s1; i += 256) {
        int s = src[i], d = dst[i];
        float x = s_l[s] + s_r[d];
        float e = (x > 0.f) ? x : ALPHA * x;
        unsigned pos = atomicAdd(&cur[((unsigned)d) >> BBITS], 1u);
        staged[pos] = make_uint2((unsigned)s | (((unsigned)d & (BSIZE - 1)) << 20),
                                 __float_as_uint(e));
    }
}

// ---------- bsort: per-bucket (128 dsts) counting sort + softmax ----------
// Single global read: records live in registers across histogram+scan.
// Softmax: one exp per record (w stored in pass B, scaled in pass C).
__global__ __launch_bounds__(256) void bsort_kernel(
        uint2* __restrict__ staged, const unsigned* __restrict__ S,
        const unsigned* __restrict__ partials,
        unsigned* __restrict__ offsets, int N, int E, int nbucket, int NB) {
    __shared__ uint2 rec[CAP];
    __shared__ unsigned pscan[512];
    __shared__ unsigned tsh[256];
    __shared__ unsigned cnt[BSIZE], incl[BSIZE], cur[BSIZE];
    const int k = blockIdx.x;
    const int t = threadIdx.x;
    local_pscan4(partials, pscan, tsh, NB, t);
    unsigned idx0 = (unsigned)k * NBLK;
    unsigned gstart = S[idx0] + pscan[idx0 >> 10];
    unsigned gend = (k + 1 == nbucket) ? (unsigned)E
                                       : (S[idx0 + NBLK] + pscan[(idx0 + NBLK) >> 10]);
    int n = (int)(gend - gstart);
    if (n > CAP) n = CAP;   // statistically impossible; avoid corruption

    if (t < BSIZE) cnt[t] = 0u;
    __syncthreads();
    // single global read: hold records in registers (static index) + histogram
    uint2 rr[REGN];
    #pragma unroll
    for (int q = 0; q < REGN; ++q) {
        int i = t + q * 256;
        if (i < n) {
            rr[q] = staged[gstart + i];
            atomicAdd(&cnt[rr[q].x >> 20], 1u);
        }
    }
    __syncthreads();
    if (t < BSIZE) incl[t] = cnt[t];
    __syncthreads();
    for (int off = 1; off < BSIZE; off <<= 1) {
        unsigned u = (t < BSIZE && t >= off) ? incl[t - off] : 0u;
        __syncthreads();
        if (t < BSIZE) incl[t] += u;
        __syncthreads();
    }
    if (t < BSIZE) cur[t] = incl[t] - cnt[t];   // start offset
    __syncthreads();
    // placement from registers
    #pragma unroll
    for (int q = 0; q < REGN; ++q) {
        int i = t + q * 256;
        if (i < n) {
            unsigned p = atomicAdd(&cur[rr[q].x >> 20], 1u);
            rec[p] = rr[q];
        }
    }
    __syncthreads();
    int d = k * BSIZE + t;
    if (t < BSIZE && d < N) {
        int b0 = (int)(incl[t] - cnt[t]);
        int c = (int)cnt[t];
        float m = -1e30f;
        for (int j = 0; j < c; ++j) m = fmaxf(m, __uint_as_float(rec[b0 + j].y));
        float sum = 0.f;
        for (int j = 0; j < c; ++j) {
            float w = __expf(__uint_as_float(rec[b0 + j].y) - m);
            sum += w;
            rec[b0 + j].y = __float_as_uint(w);
        }
        float rden = (c > 0) ? 1.f / sum : 0.f;
        for (int j = 0; j < c; ++j)
            rec[b0 + j].y = __float_as_uint(__uint_as_float(rec[b0 + j].y) * rden);
        offsets[d] = gstart + incl[t];
    }
    __syncthreads();
    for (int i = t; i < n; i += 256) {
        uint2 r = rec[i];
        staged[gstart + i] = make_uint2(r.x & 0xFFFFFu, r.y);
    }
}

// ---------- aggregate: weighted gather, wave per node ----------
__global__ __launch_bounds__(256) void aggregate_kernel(
        const uint2* __restrict__ edata, const unsigned* __restrict__ offsets,
        const unsigned short* __restrict__ ftb, float* __restrict__ out, int N) {
    __shared__ uint2 elds[ESLOTS];
    const int wv = threadIdx.x >> 6;
    const int lane = threadIdx.x & 63;
    const int eh = lane >> 4;          // edge slot 0..3
    const int j  = lane & 15;          // feat group: feats j*8 .. j*8+7
    const int db = blockIdx.x * 4;
    const int d = db + wv;

    const unsigned bstart = (db == 0) ? 0u : offsets[db - 1];
    const unsigned bend = offsets[min(db + 3, N - 1)];
    unsigned start = 0u, end = 0u;
    if (d < N) {
        start = (d == 0) ? 0u : offsets[d - 1];
        end = offsets[d];
    }

    f32x2 acc2[4];
    #pragma unroll
    for (int p = 0; p < 4; ++p) acc2[p] = (f32x2)(0.f);

    for (unsigned cbase = bstart; cbase < bend; cbase += ESLOTS) {
        const unsigned cn = min((unsigned)ESLOTS, bend - cbase);
        __syncthreads();
        for (unsigned i = threadIdx.x; i < cn; i += 256)
            elds[i] = edata[cbase + i];
        __syncthreads();
        const unsigned lo = (start > cbase) ? start : cbase;
        const unsigned hi = (end < cbase + cn) ? end : (cbase + cn);
        for (unsigned e = lo; e < hi; e += 16) {
            unsigned i0 = e + eh, i1 = e + 4 + eh, i2 = e + 8 + eh, i3 = e + 12 + eh;
            uint2 e0 = (i0 < hi) ? elds[i0 - cbase] : make_uint2(0u, 0u);  // a=0 pad
            uint2 e1 = (i1 < hi) ? elds[i1 - cbase] : make_uint2(0u, 0u);
            uint2 e2 = (i2 < hi) ? elds[i2 - cbase] : make_uint2(0u, 0u);
            uint2 e3 = (i3 < hi) ? elds[i3 - cbase] : make_uint2(0u, 0u);
            uint4 q0 = *(const uint4*)(ftb + ((unsigned)(e0.x << 7) + (j << 3)));
            uint4 q1 = *(const uint4*)(ftb + ((unsigned)(e1.x << 7) + (j << 3)));
            uint4 q2 = *(const uint4*)(ftb + ((unsigned)(e2.x << 7) + (j << 3)));
            uint4 q3 = *(const uint4*)(ftb + ((unsigned)(e3.x << 7) + (j << 3)));
            float a0 = __uint_as_float(e0.y);
            float a1 = __uint_as_float(e1.y);
            float a2 = __uint_as_float(e2.y);
            float a3 = __uint_as_float(e3.y);
            const unsigned* w0 = (const unsigned*)&q0;
            const unsigned* w1 = (const unsigned*)&q1;
            const unsigned* w2 = (const unsigned*)&q2;
            const unsigned* w3 = (const unsigned*)&q3;
            #pragma unroll
            for (int p = 0; p < 4; ++p) {
                f32x2 v0 = { __uint_as_float(w0[p] << 16), __uint_as_float(w0[p] & 0xFFFF0000u) };
                f32x2 v1 = { __uint_as_float(w1[p] << 16), __uint_as_float(w1[p] & 0xFFFF0000u) };
                f32x2 v2 = { __uint_as_float(w2[p] << 16), __uint_as_float(w2[p] & 0xFFFF0000u) };
                f32x2 v3 = { __uint_as_float(w3[p] << 16), __uint_as_float(w3[p] & 0xFFFF0000u) };
                acc2[p] += v0 * a0;
                acc2[p] += v1 * a1;
                acc2[p] += v2 * a2;
                acc2[p] += v3 * a3;
            }
        }
    }
    float acc[8];
    #pragma unroll
    for (int p = 0; p < 4; ++p) { acc[2 * p] = acc2[p][0]; acc[2 * p + 1] = acc2[p][1]; }
    #pragma unroll
    for (int p = 0; p < 8; ++p) {
        acc[p] += __shfl_xor(acc[p], 16, 64);
        acc[p] += __shfl_xor(acc[p], 32, 64);
    }
    if (d < N && eh == 0) {
        float4* op = (float4*)(out + (size_t)d * 128 + j * 8);
        op[0] = make_float4(acc[0], acc[1], acc[2], acc[3]);
        op[1] = make_float4(acc[4], acc[5], acc[6], acc[7]);
    }
}

static inline size_t align256(size_t x) { return (x + 255) & ~(size_t)255; }

extern "C" void kernel_launch(void* const* d_in, const int* in_sizes, int n_in,
                              void* d_out, int out_size, void* d_ws, size_t ws_size,
                              hipStream_t stream) {
    const float* inputs = (const float*)d_in[0];
    const int*   src    = (const int*)d_in[1];
    const int*   dst    = (const int*)d_in[2];
    const float* fc_w   = (const float*)d_in[3];
    const float* attn_l = (const float*)d_in[4];
    const float* attn_r = (const float*)d_in[5];
    float* out = (float*)d_out;

    const int N = in_sizes[0] / 128;
    const int E = in_sizes[1];
    const int nbucket = (N + BSIZE - 1) / BSIZE;       // 782
    const int M = nbucket * NBLK;                      // 400384
    const int NB1 = (M + 1023) / 1024;                 // 391 (<=512 pscan cap)
    const int slice = (E + NBLK - 1) / NBLK;
    const int GB = (N + 127) / 128;                    // gemm blocks (BM=128)

    char* w = (char*)d_ws;
    unsigned short* ftb = (unsigned short*)w;  w += align256((size_t)N * 128 * 2);
    float*    s_l      = (float*)w;     w += align256((size_t)N * 4);
    float*    s_r      = (float*)w;     w += align256((size_t)N * 4);
    unsigned* bh       = (unsigned*)w;  w += align256((size_t)M * 4);
    unsigned* S        = (unsigned*)w;  w += align256((size_t)M * 4);
    unsigned* partials = (unsigned*)w;  w += align256(1024 * 4);
    unsigned* offsets  = (unsigned*)w;  w += align256((size_t)N * 4);
    uint2*    staged   = (uint2*)w;     w += align256((size_t)E * 8);  // final edata

    front_kernel<<<GB + NBLK, 256, 0, stream>>>(inputs, fc_w, attn_l, attn_r,
                                                ftb, s_l, s_r, N, GB,
                                                dst, bh, E, nbucket, slice);
    scan1_kernel<<<NB1, 256, 0, stream>>>(bh, S, partials, M);
    bscatter_kernel<<<NBLK, 256, 0, stream>>>(src, dst, s_l, s_r, S, partials,
                                              staged, E, nbucket, slice, NB1);
    bsort_kernel<<<nbucket, 256, 0, stream>>>(staged, S, partials, offsets,
                                              N, E, nbucket, NB1);
    aggregate_kernel<<<(N + 3) / 4, 256, 0, stream>>>(staged, offsets, ftb, out, N);
}

// Round 11
// 233.616 us; speedup vs baseline: 1.0468x; 1.0468x over previous
//
#include <hip/hip_runtime.h>

// GAT forward — MFMA GEMM + two-level bucket CSR + weighted gather (5 launches):
//   1. front (fused): blocks [0,GB): MFMA gemm BM=64 -> ftb + head-0 scores
//      (W_lds built in-block; A fragments direct from global; W_lds reused
//       for C transpose);
//      blocks [GB,GB+NBLK): bhist per-(block,bucket) LDS histogram (bucket=dst>>7)
//   2. scan1: exclusive scan of bh[bucket][block] per 1024-chunk + raw totals
//   3. bscatter (512 thr): local pscan; 4-edge batched loop (8 gathers in
//      flight); cur[] init at base offset. 512 thr/block -> 16 waves/CU
//      (vs 8) with NO scan-size growth (R7's mistake avoided).
//   4. bsort (512 thr): per-bucket (128 dsts) counting sort; single global
//      read (REGN=6 records in registers); softmax 1 exp/record.
//      24 waves/CU vs 12.
//   5. aggregate: block=4 waves=4 consecutive dsts; edata staged to LDS;
//      16 lanes/edge x 4 slots; f32x2 accumulate.
//
// ws: ftb | s_l | s_r | bh (M u32) | S (M u32) | partials (1024) |
//     offsets (N u32) | staged/edata (E uint2)

#define ALPHA 0.2f
#define NBLK 512           // partition blocks
#define BBITS 7
#define BSIZE 128          // dsts per bucket
#define CAP 2816           // bsort LDS record capacity (mean 2048, +17 sigma)
#define REGN 6             // ceil(CAP/512) register-held records per thread
#define ESLOTS 1024        // aggregate edata LDS staging slots (mean span 64)

typedef __attribute__((ext_vector_type(8))) short bf16x8;
typedef __attribute__((ext_vector_type(8))) unsigned short u16x8;
typedef __attribute__((ext_vector_type(4))) float f32x4;
typedef __attribute__((ext_vector_type(2))) float f32x2;

__device__ __forceinline__ unsigned short f2bf(float f) {
    unsigned u = __float_as_uint(f);
    unsigned r = (u + 0x7FFFu + ((u >> 16) & 1u)) >> 16;   // RNE
    return (unsigned short)r;
}

// ---------- front: fused MFMA GEMM (BM=64) + bhist ----------
__global__ __launch_bounds__(256) void front_kernel(
        const float* __restrict__ A, const float* __restrict__ W,
        const float* __restrict__ attn_l, const float* __restrict__ attn_r,
        unsigned short* __restrict__ ftb,
        float* __restrict__ s_l, float* __restrict__ s_r, int N, int GB,
        const int* __restrict__ dst, unsigned* __restrict__ bh,
        int E, int nbucket, int slice) {
    __shared__ char smem[32768];
    const int tid = threadIdx.x;

    if (blockIdx.x >= (unsigned)GB) {
        // ---------------- bhist body ----------------
        unsigned* cnt = (unsigned*)smem;
        for (int i = tid; i < nbucket; i += 256) cnt[i] = 0u;
        __syncthreads();
        const int b = blockIdx.x - GB;
        int s0 = b * slice, s1 = min(s0 + slice, E);
        for (int i = s0 + tid; i < s1; i += 256)
            atomicAdd(&cnt[((unsigned)dst[i]) >> BBITS], 1u);
        __syncthreads();
        for (int k = tid; k < nbucket; k += 256)
            bh[(size_t)k * NBLK + b] = cnt[k];
        return;
    }

    // ---------------- gemm body ----------------
    u16x8* W_lds = (u16x8*)smem;                 // 128 n x 16 chunks (32 KB)
    const int block_row = blockIdx.x * 64;

    // build swizzled bf16 W^T in-block; coalesced over n, L2-served
    for (int i = tid; i < 2048; i += 256) {
        int n = i & 127, c = i >> 7;
        u16x8 v;
        #pragma unroll
        for (int j = 0; j < 8; ++j) v[j] = f2bf(W[(c * 8 + j) * 128 + n]);
        W_lds[n * 16 + (c ^ (n & 7))] = v;
    }

    const int wv = tid >> 6;
    const int lane = tid & 63;
    const int lm = lane & 15;
    const int quad = lane >> 4;
    const int am = block_row + wv * 16 + lm;     // global A row for this lane
    const bool rowok = (am < N);

    // A fragments direct from global (16B/lane contiguous per k-chunk)
    bf16x8 a_frag[4];
    #pragma unroll
    for (int ks = 0; ks < 4; ++ks) {
        int c = ks * 4 + quad;
        float4 v0 = make_float4(0.f, 0.f, 0.f, 0.f), v1 = v0;
        if (rowok) {
            const float4* p = (const float4*)(A + (size_t)am * 128 + c * 8);
            v0 = p[0]; v1 = p[1];
        }
        u16x8 u;
        u[0] = f2bf(v0.x); u[1] = f2bf(v0.y); u[2] = f2bf(v0.z); u[3] = f2bf(v0.w);
        u[4] = f2bf(v1.x); u[5] = f2bf(v1.y); u[6] = f2bf(v1.z); u[7] = f2bf(v1.w);
        a_frag[ks] = *(const bf16x8*)&u;
    }
    __syncthreads();   // W_lds ready

    f32x4 acc[8];
    #pragma unroll
    for (int t = 0; t < 8; ++t) acc[t] = (f32x4)(0.f);

    #pragma unroll
    for (int ks = 0; ks < 4; ++ks) {
        int c = ks * 4 + quad;
        #pragma unroll
        for (int t = 0; t < 8; ++t) {
            int n = t * 16 + lm;
            bf16x8 bf = *(const bf16x8*)&W_lds[n * 16 + (c ^ (n & 7))];
            acc[t] = __builtin_amdgcn_mfma_f32_16x16x32_bf16(a_frag[ks], bf, acc[t], 0, 0, 0);
        }
    }

    // fused head-0 scores (cols 0..31 live in frags 0,1)
    {
        float al0 = attn_l[lm], al1 = attn_l[16 + lm];
        float ar0 = attn_r[lm], ar1 = attn_r[16 + lm];
        #pragma unroll
        for (int r = 0; r < 4; ++r) {
            float pl = acc[0][r] * al0 + acc[1][r] * al1;
            float pr = acc[0][r] * ar0 + acc[1][r] * ar1;
            #pragma unroll
            for (int mask = 1; mask < 16; mask <<= 1) {
                pl += __shfl_xor(pl, mask, 64);
                pr += __shfl_xor(pr, mask, 64);
            }
            if (lm == 0) {
                int row = block_row + wv * 16 + quad * 4 + r;
                if (row < N) { s_l[row] = pl; s_r[row] = pr; }
            }
        }
    }

    // transpose C through LDS (reusing W_lds), then coalesced bf16 store
    __syncthreads();   // all waves done reading W_lds
    unsigned short* C_lds = (unsigned short*)smem;
    #pragma unroll
    for (int t = 0; t < 8; ++t) {
        #pragma unroll
        for (int r = 0; r < 4; ++r) {
            int mrow = wv * 16 + quad * 4 + r;
            C_lds[mrow * 128 + t * 16 + lm] = f2bf(acc[t][r]);
        }
    }
    __syncthreads();
    for (int l = tid; l < 1024; l += 256) {
        int m = l >> 4, c = l & 15;
        int row = block_row + m;
        if (row < N)
            *(u16x8*)(ftb + (size_t)row * 128 + c * 8) = *(const u16x8*)&C_lds[m * 128 + c * 8];
    }
}

// ---------- scan1: block-local exclusive scan (1024/block) + raw totals ----------
__global__ __launch_bounds__(256) void scan1_kernel(const unsigned* __restrict__ counts,
                                                    unsigned* __restrict__ S,
                                                    unsigned* __restrict__ partials, int M) {
    __shared__ unsigned sh[256];
    const int tid = threadIdx.x;
    const int base = blockIdx.x * 1024 + tid * 4;
    unsigned v[4];
    unsigned s = 0;
    #pragma unroll
    for (int k = 0; k < 4; ++k) {
        int idx = base + k;
        v[k] = (idx < M) ? counts[idx] : 0u;
        s += v[k];
    }
    sh[tid] = s;
    __syncthreads();
    for (int off = 1; off < 256; off <<= 1) {
        unsigned t = (tid >= off) ? sh[tid - off] : 0u;
        __syncthreads();
        sh[tid] += t;
        __syncthreads();
    }
    if (tid == 255) partials[blockIdx.x] = sh[255];   // RAW total (no scan2)
    unsigned run = (tid == 0) ? 0u : sh[tid - 1];
    #pragma unroll
    for (int k = 0; k < 4; ++k) {
        int idx = base + k;
        if (idx < M) S[idx] = run;
        run += v[k];
    }
}

// local exclusive scan of <=512 raw partials into pscan[] (512-thread blocks)
__device__ __forceinline__ void local_pscan512(const unsigned* __restrict__ partials,
                                               unsigned* pscan, int NB, int tid) {
    unsigned v = (tid < NB) ? partials[tid] : 0u;
    pscan[tid] = v;
    __syncthreads();
    for (int off = 1; off < 512; off <<= 1) {
        unsigned t = (tid >= off) ? pscan[tid - off] : 0u;
        __syncthreads();
        pscan[tid] += t;
        __syncthreads();
    }
    unsigned excl = (tid == 0) ? 0u : pscan[tid - 1];
    __syncthreads();
    pscan[tid] = excl;
    __syncthreads();
}

// ---------- bscatter (512 thr): staged[pos] = {src | dlow<<20, leaky} ----------
// cur[k] initialized AT the global base; 4-edge batched loop keeps 8 random
// gathers in flight per lane. 512 threads/block -> 16 waves/CU at NBLK=512.
__global__ __launch_bounds__(512) void bscatter_kernel(
        const int* __restrict__ src, const int* __restrict__ dst,
        const float* __restrict__ s_l, const float* __restrict__ s_r,
        const unsigned* __restrict__ S, const unsigned* __restrict__ partials,
        uint2* __restrict__ staged, int E, int nbucket, int slice, int NB) {
    __shared__ unsigned pscan[512];
    __shared__ unsigned cur[800];
    const int b = blockIdx.x;
    const int tid = threadIdx.x;
    local_pscan512(partials, pscan, NB, tid);
    for (int k = tid; k < nbucket; k += 512) {
        unsigned idx = (unsigned)k * NBLK + b;
        cur[k] = S[idx] + pscan[idx >> 10];
    }
    __syncthreads();
    const int s0 = b * slice, s1 = min(s0 + slice, E);
    int i = s0 + tid;
    // 4-edge batched steady loop: all loads issued before any compute
    for (; i + 1536 < s1; i += 2048) {
        int sa = src[i],        da = dst[i];
        int sb = src[i + 512],  db = dst[i + 512];
        int sc = src[i + 1024], dc = dst[i + 1024];
        int sd = src[i + 1536], dd = dst[i + 1536];
        float la = s_l[sa], ra = s_r[da];
        float lb = s_l[sb], rb = s_r[db];
        float lc = s_l[sc], rc = s_r[dc];
        float ld = s_l[sd], rd = s_r[dd];
        float xa = la + ra, xb = lb + rb, xc = lc + rc, xd = ld + rd;
        float ea = (xa > 0.f) ? xa : ALPHA * xa;
        float eb = (xb > 0.f) ? xb : ALPHA * xb;
        float ec = (xc > 0.f) ? xc : ALPHA * xc;
        float ed = (xd > 0.f) ? xd : ALPHA * xd;
        unsigned pa = atomicAdd(&cur[((unsigned)da) >> BBITS], 1u);
        unsigned pb = atomicAdd(&cur[((unsigned)db) >> BBITS], 1u);
        unsigned pc = atomicAdd(&cur[((unsigned)dc) >> BBITS], 1u);
        unsigned pd = atomicAdd(&cur[((unsigned)dd) >> BBITS], 1u);
        staged[pa] = make_uint2((unsigned)sa | (((unsigned)da & (BSIZE - 1)) << 20), __float_as_uint(ea));
        staged[pb] = make_uint2((unsigned)sb | (((unsigned)db & (BSIZE - 1)) << 20), __float_as_uint(eb));
        staged[pc] = make_uint2((unsigned)sc | (((unsigned)dc & (BSIZE - 1)) << 20), __float_as_uint(ec));
        staged[pd] = make_uint2((unsigned)sd | (((unsigned)dd & (BSIZE - 1)) << 20), __float_as_uint(ed));
    }
    for (; i < s1; i += 512) {
        int s = src[i], d = dst[i];
        float x = s_l[s] + s_r[d];
        float e = (x > 0.f) ? x : ALPHA * x;
        unsigned pos = atomicAdd(&cur[((unsigned)d) >> BBITS], 1u);
        staged[pos] = make_uint2((unsigned)s | (((unsigned)d & (BSIZE - 1)) << 20),
                                 __float_as_uint(e));
    }
}

// ---------- bsort (512 thr): per-bucket (128 dsts) counting sort + softmax ----------
// Single global read: records in registers (REGN=6). Softmax: 1 exp/record.
__global__ __launch_bounds__(512) void bsort_kernel(
        uint2* __restrict__ staged, const unsigned* __restrict__ S,
        const unsigned* __restrict__ partials,
        unsigned* __restrict__ offsets, int N, int E, int nbucket, int NB) {
    __shared__ uint2 rec[CAP];
    __shared__ unsigned pscan[512];
    __shared__ unsigned cnt[BSIZE], incl[BSIZE], cur[BSIZE];
    const int k = blockIdx.x;
    const int t = threadIdx.x;
    local_pscan512(partials, pscan, NB, t);
    unsigned idx0 = (unsigned)k * NBLK;
    unsigned gstart = S[idx0] + pscan[idx0 >> 10];
    unsigned gend = (k + 1 == nbucket) ? (unsigned)E
                                       : (S[idx0 + NBLK] + pscan[(idx0 + NBLK) >> 10]);
    int n = (int)(gend - gstart);
    if (n > CAP) n = CAP;   // statistically impossible; avoid corruption

    if (t < BSIZE) cnt[t] = 0u;
    __syncthreads();
    // single global read: hold records in registers (static index) + histogram
    uint2 rr[REGN];
    #pragma unroll
    for (int q = 0; q < REGN; ++q) {
        int i = t + q * 512;
        if (i < n) {
            rr[q] = staged[gstart + i];
            atomicAdd(&cnt[rr[q].x >> 20], 1u);
        }
    }
    __syncthreads();
    if (t < BSIZE) incl[t] = cnt[t];
    __syncthreads();
    for (int off = 1; off < BSIZE; off <<= 1) {
        unsigned u = (t < BSIZE && t >= off) ? incl[t - off] : 0u;
        __syncthreads();
        if (t < BSIZE) incl[t] += u;
        __syncthreads();
    }
    if (t < BSIZE) cur[t] = incl[t] - cnt[t];   // start offset
    __syncthreads();
    // placement from registers
    #pragma unroll
    for (int q = 0; q < REGN; ++q) {
        int i = t + q * 512;
        if (i < n) {
            unsigned p = atomicAdd(&cur[rr[q].x >> 20], 1u);
            rec[p] = rr[q];
        }
    }
    __syncthreads();
    int d = k * BSIZE + t;
    if (t < BSIZE && d < N) {
        int b0 = (int)(incl[t] - cnt[t]);
        int c = (int)cnt[t];
        float m = -1e30f;
        for (int j = 0; j < c; ++j) m = fmaxf(m, __uint_as_float(rec[b0 + j].y));
        float sum = 0.f;
        for (int j = 0; j < c; ++j) {
            float w = __expf(__uint_as_float(rec[b0 + j].y) - m);
            sum += w;
            rec[b0 + j].y = __float_as_uint(w);
        }
        float rden = (c > 0) ? 1.f / sum : 0.f;
        for (int j = 0; j < c; ++j)
            rec[b0 + j].y = __float_as_uint(__uint_as_float(rec[b0 + j].y) * rden);
        offsets[d] = gstart + incl[t];
    }
    __syncthreads();
    for (int i = t; i < n; i += 512) {
        uint2 r = rec[i];
        staged[gstart + i] = make_uint2(r.x & 0xFFFFFu, r.y);
    }
}

// ---------- aggregate: weighted gather, wave per node ----------
__global__ __launch_bounds__(256) void aggregate_kernel(
        const uint2* __restrict__ edata, const unsigned* __restrict__ offsets,
        const unsigned short* __restrict__ ftb, float* __restrict__ out, int N) {
    __shared__ uint2 elds[ESLOTS];
    const int wv = threadIdx.x >> 6;
    const int lane = threadIdx.x & 63;
    const int eh = lane >> 4;          // edge slot 0..3
    const int j  = lane & 15;          // feat group: feats j*8 .. j*8+7
    const int db = blockIdx.x * 4;
    const int d = db + wv;

    const unsigned bstart = (db == 0) ? 0u : offsets[db - 1];
    const unsigned bend = offsets[min(db + 3, N - 1)];
    unsigned start = 0u, end = 0u;
    if (d < N) {
        start = (d == 0) ? 0u : offsets[d - 1];
        end = offsets[d];
    }

    f32x2 acc2[4];
    #pragma unroll
    for (int p = 0; p < 4; ++p) acc2[p] = (f32x2)(0.f);

    for (unsigned cbase = bstart; cbase < bend; cbase += ESLOTS) {
        const unsigned cn = min((unsigned)ESLOTS, bend - cbase);
        __syncthreads();
        for (unsigned i = threadIdx.x; i < cn; i += 256)
            elds[i] = edata[cbase + i];
        __syncthreads();
        const unsigned lo = (start > cbase) ? start : cbase;
        const unsigned hi = (end < cbase + cn) ? end : (cbase + cn);
        for (unsigned e = lo; e < hi; e += 16) {
            unsigned i0 = e + eh, i1 = e + 4 + eh, i2 = e + 8 + eh, i3 = e + 12 + eh;
            uint2 e0 = (i0 < hi) ? elds[i0 - cbase] : make_uint2(0u, 0u);  // a=0 pad
            uint2 e1 = (i1 < hi) ? elds[i1 - cbase] : make_uint2(0u, 0u);
            uint2 e2 = (i2 < hi) ? elds[i2 - cbase] : make_uint2(0u, 0u);
            uint2 e3 = (i3 < hi) ? elds[i3 - cbase] : make_uint2(0u, 0u);
            uint4 q0 = *(const uint4*)(ftb + ((unsigned)(e0.x << 7) + (j << 3)));
            uint4 q1 = *(const uint4*)(ftb + ((unsigned)(e1.x << 7) + (j << 3)));
            uint4 q2 = *(const uint4*)(ftb + ((unsigned)(e2.x << 7) + (j << 3)));
            uint4 q3 = *(const uint4*)(ftb + ((unsigned)(e3.x << 7) + (j << 3)));
            float a0 = __uint_as_float(e0.y);
            float a1 = __uint_as_float(e1.y);
            float a2 = __uint_as_float(e2.y);
            float a3 = __uint_as_float(e3.y);
            const unsigned* w0 = (const unsigned*)&q0;
            const unsigned* w1 = (const unsigned*)&q1;
            const unsigned* w2 = (const unsigned*)&q2;
            const unsigned* w3 = (const unsigned*)&q3;
            #pragma unroll
            for (int p = 0; p < 4; ++p) {
                f32x2 v0 = { __uint_as_float(w0[p] << 16), __uint_as_float(w0[p] & 0xFFFF0000u) };
                f32x2 v1 = { __uint_as_float(w1[p] << 16), __uint_as_float(w1[p] & 0xFFFF0000u) };
                f32x2 v2 = { __uint_as_float(w2[p] << 16), __uint_as_float(w2[p] & 0xFFFF0000u) };
                f32x2 v3 = { __uint_as_float(w3[p] << 16), __uint_as_float(w3[p] & 0xFFFF0000u) };
                acc2[p] += v0 * a0;
                acc2[p] += v1 * a1;
                acc2[p] += v2 * a2;
                acc2[p] += v3 * a3;
            }
        }
    }
    float acc[8];
    #pragma unroll
    for (int p = 0; p < 4; ++p) { acc[2 * p] = acc2[p][0]; acc[2 * p + 1] = acc2[p][1]; }
    #pragma unroll
    for (int p = 0; p < 8; ++p) {
        acc[p] += __shfl_xor(acc[p], 16, 64);
        acc[p] += __shfl_xor(acc[p], 32, 64);
    }
    if (d < N && eh == 0) {
        float4* op = (float4*)(out + (size_t)d * 128 + j * 8);
        op[0] = make_float4(acc[0], acc[1], acc[2], acc[3]);
        op[1] = make_float4(acc[4], acc[5], acc[6], acc[7]);
    }
}

static inline size_t align256(size_t x) { return (x + 255) & ~(size_t)255; }

extern "C" void kernel_launch(void* const* d_in, const int* in_sizes, int n_in,
                              void* d_out, int out_size, void* d_ws, size_t ws_size,
                              hipStream_t stream) {
    const float* inputs = (const float*)d_in[0];
    const int*   src    = (const int*)d_in[1];
    const int*   dst    = (const int*)d_in[2];
    const float* fc_w   = (const float*)d_in[3];
    const float* attn_l = (const float*)d_in[4];
    const float* attn_r = (const float*)d_in[5];
    float* out = (float*)d_out;

    const int N = in_sizes[0] / 128;
    const int E = in_sizes[1];
    const int nbucket = (N + BSIZE - 1) / BSIZE;       // 782
    const int M = nbucket * NBLK;                      // 400384
    const int NB1 = (M + 1023) / 1024;                 // 391 (<=512 pscan cap)
    const int slice = (E + NBLK - 1) / NBLK;
    const int GB = (N + 63) / 64;                      // gemm blocks (BM=64)

    char* w = (char*)d_ws;
    unsigned short* ftb = (unsigned short*)w;  w += align256((size_t)N * 128 * 2);
    float*    s_l      = (float*)w;     w += align256((size_t)N * 4);
    float*    s_r      = (float*)w;     w += align256((size_t)N * 4);
    unsigned* bh       = (unsigned*)w;  w += align256((size_t)M * 4);
    unsigned* S        = (unsigned*)w;  w += align256((size_t)M * 4);
    unsigned* partials = (unsigned*)w;  w += align256(1024 * 4);
    unsigned* offsets  = (unsigned*)w;  w += align256((size_t)N * 4);
    uint2*    staged   = (uint2*)w;     w += align256((size_t)E * 8);  // final edata

    front_kernel<<<GB + NBLK, 256, 0, stream>>>(inputs, fc_w, attn_l, attn_r,
                                                ftb, s_l, s_r, N, GB,
                                                dst, bh, E, nbucket, slice);
    scan1_kernel<<<NB1, 256, 0, stream>>>(bh, S, partials, M);
    bscatter_kernel<<<NBLK, 512, 0, stream>>>(src, dst, s_l, s_r, S, partials,
                                              staged, E, nbucket, slice, NB1);
    bsort_kernel<<<nbucket, 512, 0, stream>>>(staged, S, partials, offsets,
                                              N, E, nbucket, NB1);
    aggregate_kernel<<<(N + 3) / 4, 256, 0, stream>>>(staged, offsets, ftb, out, N);
}